// Round 7
// baseline (517.069 us; speedup 1.0000x reference)
//
#include <hip/hip_runtime.h>

// SimpleRNN: T=64, B=8, H=512, I=256, O=8, G=4, GS=64
// sign: +1 for j<=408, -1 for j>=409; exist: j<410
// chunk c: j = lane + 64c. c<=5 -> +1; c==7 -> -1 (exist=0);
// c==6 -> lane<=24: +1, lane==25: -1 (exists), lane>=26: no exist.
#define T_N 64
#define B_N 8
#define H_N 512
#define I_N 256
#define O_N 8
#define G_N 4

constexpr float DT_  = 0.02f;
constexpr float AX_  = 0.2f;    // DT/0.1
constexpr float AW_  = 0.02f;   // DT/1.0
constexpr float OMAW = 1.0f - AW_;

using u32 = unsigned;
using u64 = unsigned long long;

// Agent-scope coherent ops (sc0/sc1): bypass non-coherent L1/L2 -> LLC.
__device__ __forceinline__ void stf_agent(float* p, float v) {
    __hip_atomic_store(p, v, __ATOMIC_RELAXED, __HIP_MEMORY_SCOPE_AGENT);
}
__device__ __forceinline__ u64 ld64_agent(const u64* p) {
    return __hip_atomic_load(p, __ATOMIC_RELAXED, __HIP_MEMORY_SCOPE_AGENT);
}
__device__ __forceinline__ void st64_agent(u64* p, u64 v) {
    __hip_atomic_store(p, v, __ATOMIC_RELAXED, __HIP_MEMORY_SCOPE_AGENT);
}

__device__ __forceinline__ float fast_tanh_pos(float x) {
    // x >= 0; exact at 0 and +inf. tanh(x) = 1 - 2/(e^{2x}+1)
    float ex = __expf(2.0f * x);
    return 1.0f - 2.0f / (ex + 1.0f);
}

// bf16 pair packing for static clamp-floor constants (RN-even).
__device__ __forceinline__ u32 pack_bf16(float lo, float hi) {
    u32 ul = __float_as_uint(lo), uh = __float_as_uint(hi);
    u32 rl = (ul + 0x7FFFu + ((ul >> 16) & 1u)) >> 16;
    u32 rh = (uh + 0x7FFFu + ((uh >> 16) & 1u)) >> 16;
    return (rh << 16) | (rl & 0xFFFFu);
}
__device__ __forceinline__ float unpk_lo(u32 u) { return __uint_as_float(u << 16); }
__device__ __forceinline__ float unpk_hi(u32 u) { return __uint_as_float(u & 0xFFFF0000u); }

// 64 blocks x 512 threads (8 waves). b = bk&7, kb = bk>>3 (block-in-batch).
// Wave owns 8 h: hbase = kb*64 + wid*8. Per step, each wave publishes its 8
// outputs as tagged u64 words on a wave-private 64B line (fire-and-forget);
// wave 0 of each block polls 64 lines (lane L -> line L), relays via LDS.
__global__ __launch_bounds__(512, 2) void rnn_scan(
    const float* __restrict__ x, const float* __restrict__ Rs,
    const float* __restrict__ W_x2h, const float* __restrict__ W_h2h,
    const float* __restrict__ b_h2h, const float* __restrict__ W_h2o,
    const float* __restrict__ W_attn, const float* __restrict__ b_attn,
    const float* __restrict__ kappa, float* __restrict__ d_out,
    u64* __restrict__ vals)            // [2][B][64 waves][8] tagged u64
{
    float* os = d_out;                      // [T][B][O]
    float* hs = d_out + T_N * B_N * O_N;    // [T][B][H]

    __shared__ float s_ea[G_N * H_N];       // 8 KB eff_attn
    __shared__ float s_out[H_N];            // 2 KB relay (self-synchronized)

    const int tid   = threadIdx.x;
    const int wid   = tid >> 6;             // 0..7
    const int lane  = tid & 63;
    const int bk    = blockIdx.x;           // 0..63
    const int b     = bk & 7;
    const int kb    = bk >> 3;              // 0..7
    const int kw    = (kb << 3) | wid;      // wave id within batch 0..63
    const int hbase = (kb << 6) | (wid << 3);

    // ---- eff_attn = relu(W_attn)*sign*exist into LDS ----
    for (int idx = tid; idx < G_N * H_N; idx += 512) {
        int j = idx & (H_N - 1);
        float w = fmaxf(W_attn[idx], 0.0f);
        float m = (j <= 408) ? 1.0f : ((j == 409) ? -1.0f : 0.0f);
        s_ea[idx] = w * m;
    }

    // ---- per-h persistent state (effective-weight form) ----
    // ex = Wxp + wx >= 0 ; se = sign*(Whp + wh), 0 at diagonal
    float ex[8][4]; u32 bwxp[8][2];         // bwx = AW*Wxp, bf16-packed
    float se[8][8]; u32 bwhp[8][4];         // bwh = AW*Whp, bf16-packed
    float st[8], bh[8];
#pragma unroll
    for (int r = 0; r < 8; ++r) {
        int h = hbase + r;
        float tx[4];
#pragma unroll
        for (int c = 0; c < 4; ++c) {
            tx[c] = fmaxf(W_x2h[h * I_N + lane + 64 * c], 0.0f);
            ex[r][c] = tx[c];
        }
        bwxp[r][0] = pack_bf16(AW_ * tx[0], AW_ * tx[1]);
        bwxp[r][1] = pack_bf16(AW_ * tx[2], AW_ * tx[3]);
        float th[8];
#pragma unroll
        for (int c = 0; c < 8; ++c) {
            int j = lane + 64 * c;
            float w = fmaxf(W_h2h[h * H_N + j], 0.0f);
            float s = (j <= 408) ? 1.0f : -1.0f;
            se[r][c] = (j == h) ? 0.0f : s * w;
            th[c] = AW_ * w;
        }
#pragma unroll
        for (int q = 0; q < 4; ++q) bwhp[r][q] = pack_bf16(th[2 * q], th[2 * q + 1]);
        st[r] = 0.0f;
        bh[r] = b_h2h[h];
    }
    const float k0 = kappa[0], k1 = kappa[1], k2 = kappa[2];
    const float k3 = kappa[3], k4 = kappa[4], k5 = kappa[5];
    const float ba0 = b_attn[0], ba1 = b_attn[1], ba2 = b_attn[2], ba3 = b_attn[3];

    float xv[4];
#pragma unroll
    for (int c = 0; c < 4; ++c) xv[c] = fmaxf(x[(size_t)b * I_N + lane + 64 * c], 0.0f);
    float Rcur = Rs[b];

    float outp[8];
#pragma unroll
    for (int c = 0; c < 8; ++c) outp[c] = 0.0f;   // t=0 inputs are zeros

    u64* vb0 = vals + (size_t)b * (64 * 8);       // batch base, slot 0
    const size_t slot_off = (size_t)B_N * 64 * 8; // u64s per slot

    __syncthreads();                               // s_ea ready

    for (int t = 0; t < T_N; ++t) {
        u64* vbase = vb0 + (size_t)(t & 1) * slot_off;

        // ---- phase 1: attention logits (4 reductions) ----
        float l0 = 0.f, l1 = 0.f, l2 = 0.f, l3 = 0.f;
#pragma unroll
        for (int c = 0; c < 7; ++c) {             // chunk 7 is all-zero
            int j = lane + 64 * c;
            float o = outp[c];
            l0 = fmaf(o, s_ea[j], l0);
            l1 = fmaf(o, s_ea[H_N + j], l1);
            l2 = fmaf(o, s_ea[2 * H_N + j], l2);
            l3 = fmaf(o, s_ea[3 * H_N + j], l3);
        }
#pragma unroll
        for (int off = 32; off >= 1; off >>= 1) {
            l0 += __shfl_xor(l0, off, 64);
            l1 += __shfl_xor(l1, off, 64);
            l2 += __shfl_xor(l2, off, 64);
            l3 += __shfl_xor(l3, off, 64);
        }
        float e0 = __expf(l0 + ba0), e1 = __expf(l1 + ba1);
        float e2 = __expf(l2 + ba2), e3 = __expf(l3 + ba3);
        float inv = 4.0f / (e0 + e1 + e2 + e3);   // fold *G
        float xin[4] = { xv[0] * e0 * inv, xv[1] * e1 * inv,
                         xv[2] * e2 * inv, xv[3] * e3 * inv };

        // ---- phase 2: per-h totals (8 reductions) ----
        float d[8];
#pragma unroll
        for (int r = 0; r < 8; ++r) {
            float a = ex[r][0] * xin[0];
            a = fmaf(ex[r][1], xin[1], a);
            a = fmaf(ex[r][2], xin[2], a);
            a = fmaf(ex[r][3], xin[3], a);
#pragma unroll
            for (int c = 0; c < 8; ++c) a = fmaf(se[r][c], outp[c], a);
            d[r] = a;
        }
#pragma unroll
        for (int off = 32; off >= 1; off >>= 1) {
#pragma unroll
            for (int r = 0; r < 8; ++r) d[r] += __shfl_xor(d[r], off, 64);
        }

        float no[8];
#pragma unroll
        for (int r = 0; r < 8; ++r) {
            st[r] = st[r] * (1.0f - AX_) + (d[r] + bh[r]) * AX_;
            no[r] = fast_tanh_pos(fmaxf(st[r], 0.0f));
        }

        // ---- publish: lane r stores h = hbase+r (static select chain) ----
        float myno = no[0];
#pragma unroll
        for (int r = 1; r < 8; ++r) myno = (lane == r) ? no[r] : myno;
        float* hrow = hs + ((size_t)t * B_N + b) * H_N;
        u64* myline = vbase + (size_t)kw * 8;
        u64 tagged = ((u64)(u32)(t + 1) << 32) | (u64)__float_as_uint(myno);
        if (t < T_N - 1) {
            if (lane < 8) {
                st64_agent(myline + lane, tagged);      // signal+value, one store
                stf_agent(hrow + hbase + lane, myno);   // output, fire-and-forget
            }
        } else {
            if (lane < 8) stf_agent(hrow + hbase + lane, myno);
            asm volatile("s_waitcnt vmcnt(0)" ::: "memory"); // drain ALL hs stores
            if (lane < 8) st64_agent(myline + lane, tagged); // tag 64 = release
        }

        // ---- plasticity (uses OLD outp) + input prefetch, as lambdas ----
        float xvn[4] = {0.f, 0.f, 0.f, 0.f};
        float Rn = 0.0f;
        auto plast = [&]() {
            float dr = DT_ * Rcur;
#pragma unroll
            for (int r = 0; r < 8; ++r) {
                float k1n = k1 * no[r], k2n = k2 * no[r];
                float k4n = k4 * no[r], k5n = k5 * no[r];
#pragma unroll
                for (int c = 0; c < 4; ++c) {
                    float bw = (c & 1) ? unpk_hi(bwxp[r][c >> 1]) : unpk_lo(bwxp[r][c >> 1]);
                    float hx = fmaf(k2n, xin[c], fmaf(k0, xin[c], k1n));
                    ex[r][c] = fmaxf(fmaf(ex[r][c], OMAW, fmaf(dr, hx, bw)), 0.0f);
                }
#pragma unroll
                for (int c = 0; c < 8; ++c) {
                    float bw = (c & 1) ? unpk_hi(bwhp[r][c >> 1]) : unpk_lo(bwhp[r][c >> 1]);
                    float hh = fmaf(k5n, outp[c], fmaf(k3, outp[c], k4n));
                    float a = se[r][c] * OMAW, p = fmaf(dr, hh, bw);
                    float v;
                    if (c <= 5)      v = fmaxf(a + p, 0.0f);
                    else if (c == 7) v = fminf(a - p, 0.0f);
                    else             v = (lane <= 24) ? fmaxf(a + p, 0.0f)
                                                      : fminf(a - p, 0.0f);
                    if (c == kb && lane == ((wid << 3) | r)) v = 0.0f;  // diagonal
                    se[r][c] = v;
                }
            }
        };
        auto pf = [&]() {
            if (t + 1 < T_N) {
                const float* xr = x + ((size_t)(t + 1) * B_N + b) * I_N;
#pragma unroll
                for (int c = 0; c < 4; ++c) xvn[c] = xr[lane + 64 * c];
                Rn = Rs[(t + 1) * B_N + b];
            }
        };

        // ---- wave 0 polls (lane L -> wave-line L); others do plasticity ----
        if (wid == 0) {
            const u64* pline = vbase + (size_t)lane * 8;
            const u32 want = (u32)(t + 1);
            u32 vw[8]; u32 done = 0;
            while (true) {
#pragma unroll
                for (int c = 0; c < 8; ++c) {
                    if (!((done >> c) & 1u)) {
                        u64 pk = ld64_agent(pline + c);
                        if ((u32)(pk >> 32) == want) { vw[c] = (u32)pk; done |= 1u << c; }
                    }
                }
                if (__all(done == 0xFFu)) break;
            }
            int base = ((lane >> 3) << 6) | ((lane & 7) << 3);  // wave L's hbase
#pragma unroll
            for (int c = 0; c < 8; ++c) s_out[base + c] = __uint_as_float(vw[c]);
        } else {
            plast();
            pf();
        }
        __syncthreads();   // single barrier/step; s_out self-synchronized

        float outn[8];
        if (t + 1 < T_N) {
#pragma unroll
            for (int c = 0; c < 8; ++c) outn[c] = s_out[lane + 64 * c];
        }
        if (wid == 0) { plast(); pf(); }   // wave 0's turn (old outp preserved)
        if (t + 1 < T_N) {
#pragma unroll
            for (int c = 0; c < 8; ++c) outp[c] = outn[c];
#pragma unroll
            for (int c = 0; c < 4; ++c) xv[c] = fmaxf(xvn[c], 0.0f);
            Rcur = Rn;
        }
    }

    // ---- epilogue: wave kw handles t=kw, all 8 o. Visibility: tag-64 polls
    // happened after every wave's vmcnt(0) drain; hs lines never read before,
    // so plain cached loads fetch fresh data from LLC. ----
    {
        int te = kw;
        const float* hrow = hs + ((size_t)te * B_N + b) * H_N;
        float acc[8];
#pragma unroll
        for (int o = 0; o < 8; ++o) acc[o] = 0.0f;
#pragma unroll
        for (int c = 0; c < 7; ++c) {      // c==7 has no exist
            int j = lane + 64 * c;
            float hv = hrow[j];
#pragma unroll
            for (int o = 0; o < 8; ++o) {
                float w = fmaxf(W_h2o[o * H_N + j], 0.0f);
                if (j >= 410) w = 0.0f;    // folds: only c==6, lane>=26
                acc[o] = fmaf(hv, w, acc[o]);
            }
        }
#pragma unroll
        for (int off = 32; off >= 1; off >>= 1) {
#pragma unroll
            for (int o = 0; o < 8; ++o) acc[o] += __shfl_xor(acc[o], off, 64);
        }
        float mya = acc[0];
#pragma unroll
        for (int o = 1; o < 8; ++o) mya = (lane == o) ? acc[o] : mya;
        if (lane < 8) os[te * (B_N * O_N) + b * O_N + lane] = mya;
    }
}

extern "C" void kernel_launch(void* const* d_in, const int* in_sizes, int n_in,
                              void* d_out, int out_size, void* d_ws, size_t ws_size,
                              hipStream_t stream) {
    (void)in_sizes; (void)n_in; (void)out_size; (void)ws_size;
    const float* x      = (const float*)d_in[0];
    const float* Rs     = (const float*)d_in[1];
    const float* W_x2h  = (const float*)d_in[2];
    const float* W_h2h  = (const float*)d_in[3];
    const float* b_h2h  = (const float*)d_in[4];
    const float* W_h2o  = (const float*)d_in[5];
    const float* W_attn = (const float*)d_in[6];
    const float* b_attn = (const float*)d_in[7];
    const float* kappa  = (const float*)d_in[8];
    float* out = (float*)d_out;
    u64* vals = (u64*)d_ws;   // [2][8][64][8] u64 = 65536 B

    // zero the tagged comm words every call (tag 0 != any wanted tag)
    hipMemsetAsync(d_ws, 0, 2 * B_N * 64 * 8 * sizeof(u64), stream);
    rnn_scan<<<dim3(64), dim3(512), 0, stream>>>(
        x, Rs, W_x2h, W_h2h, b_h2h, W_h2o, W_attn, b_attn, kappa, out, vals);
}

// Round 8
// 415.810 us; speedup vs baseline: 1.2435x; 1.2435x over previous
//
#include <hip/hip_runtime.h>

// SimpleRNN: T=64, B=8, H=512, I=256, O=8, G=4, GS=64
// sign: +1 for j<=408, -1 for j>=409; exist: j<410
// chunk c: j = lane + 64c. c<=5 -> +1; c==7 -> -1 (exist=0);
// c==6 -> lane<=24: +1, lane==25: -1 (exists), lane>=26: no exist.
#define T_N 64
#define B_N 8
#define H_N 512
#define I_N 256
#define O_N 8
#define G_N 4

constexpr float DT_  = 0.02f;
constexpr float AX_  = 0.2f;    // DT/0.1
constexpr float AW_  = 0.02f;   // DT/1.0
constexpr float OMAW = 1.0f - AW_;

using u32 = unsigned;
using u64 = unsigned long long;

// Agent-scope coherent ops (sc0/sc1): bypass non-coherent L1/L2 -> LLC.
__device__ __forceinline__ u64 ld64_agent(const u64* p) {
    return __hip_atomic_load(p, __ATOMIC_RELAXED, __HIP_MEMORY_SCOPE_AGENT);
}
__device__ __forceinline__ void st64_agent(u64* p, u64 v) {
    __hip_atomic_store(p, v, __ATOMIC_RELAXED, __HIP_MEMORY_SCOPE_AGENT);
}

__device__ __forceinline__ float fast_tanh_pos(float x) {
    // x >= 0; exact at 0 and +inf. tanh(x) = 1 - 2/(e^{2x}+1)
    float ex = __expf(2.0f * x);
    return 1.0f - 2.0f / (ex + 1.0f);
}

// 256 blocks x 1024 threads; wave owns one h. b = bk&7, hg = bk>>3,
// h = hg*16 + wid. Per-step cross-block sync: producer lane0 fires ONE
// tagged u64 ((t+1)<<32 | f32bits) into vals[t&1][b][h] -- value IS the
// signal, no drain/flag/extra gather. Consumer: wave 0 only; lane L polls
// exactly line L (8 contiguous u64 = h 8L..8L+7) -> 32 poll streams per
// line (the fan-in R5 proved safe), done-mask + s_sleep backoff, poll
// starts after plasticity. Relay via double-buffered LDS, 1 barrier/step.
__global__ __launch_bounds__(1024) void rnn_scan(
    const float* __restrict__ x, const float* __restrict__ Rs,
    const float* __restrict__ W_x2h, const float* __restrict__ W_h2h,
    const float* __restrict__ b_h2h,
    const float* __restrict__ W_attn, const float* __restrict__ b_attn,
    const float* __restrict__ kappa, float* __restrict__ hs,
    u64* __restrict__ vals)            // [2][B][H] tagged u64
{
    __shared__ float s_out[2][H_N];    // double buffer: 1 barrier/step

    const int tid  = threadIdx.x;
    const int wid  = tid >> 6;         // 0..15
    const int lane = tid & 63;
    const int bk   = blockIdx.x;       // 0..255
    const int b    = bk & 7;
    const int hg   = bk >> 3;          // 0..31
    const int h    = (hg << 4) | wid;  // 0..511
    const int c_d  = h >> 6;           // chunk holding the diagonal
    const int dl   = h & 63;           // its lane

    // ---- loop-invariant constants (registers only) ----
    float ea[G_N][7];
#pragma unroll
    for (int g = 0; g < G_N; ++g)
#pragma unroll
        for (int c = 0; c < 7; ++c) {
            int j = lane + 64 * c;
            float w = fmaxf(W_attn[g * H_N + j], 0.0f);
            float m = (j <= 408) ? 1.0f : ((j == 409) ? -1.0f : 0.0f);
            ea[g][c] = w * m;
        }

    // x-side: ex = Wxp + wx (>=0); bwx = AW*Wxp
    float ex[4], bwx[4];
#pragma unroll
    for (int c = 0; c < 4; ++c) {
        ex[c]  = fmaxf(W_x2h[h * I_N + lane + 64 * c], 0.0f);
        bwx[c] = AW_ * ex[c];
    }
    // h2h: se = sign*(Whp+wh); bwh = AW*Whp
    float se[8], bwh[8];
#pragma unroll
    for (int c = 0; c < 8; ++c) {
        int j = lane + 64 * c;
        float s = (j <= 408) ? 1.0f : -1.0f;
        float w = fmaxf(W_h2h[h * H_N + j], 0.0f);
        se[c]  = (j == h) ? 0.0f : s * w;
        bwh[c] = AW_ * w;
    }
    const float bh = b_h2h[h];
    const float k0 = kappa[0], k1 = kappa[1], k2 = kappa[2];
    const float k3 = kappa[3], k4 = kappa[4], k5 = kappa[5];
    const float ba0 = b_attn[0], ba1 = b_attn[1], ba2 = b_attn[2], ba3 = b_attn[3];

    float st = 0.0f;

    float xv[4];
#pragma unroll
    for (int c = 0; c < 4; ++c) xv[c] = fmaxf(x[(size_t)b * I_N + lane + 64 * c], 0.0f);
    float Rcur = Rs[b];

    float outp[8];
#pragma unroll
    for (int c = 0; c < 8; ++c) outp[c] = 0.0f;   // t=0 inputs are zeros

    for (int t = 0; t < T_N; ++t) {
        // ---- 9 fused wave reductions: 4 attn logits, 4 x-dot group
        //      partials, 1 h2h dot ----
        float red[9];
#pragma unroll
        for (int g = 0; g < G_N; ++g) {
            float l = 0.0f;
#pragma unroll
            for (int c = 0; c < 7; ++c) l = fmaf(outp[c], ea[g][c], l);
            red[g] = l;
        }
#pragma unroll
        for (int c = 0; c < 4; ++c) red[4 + c] = ex[c] * xv[c];
        {
            float a = 0.0f;
#pragma unroll
            for (int c = 0; c < 8; ++c) a = fmaf(se[c], outp[c], a);
            red[8] = a;
        }
#pragma unroll
        for (int off = 32; off >= 1; off >>= 1) {
#pragma unroll
            for (int k = 0; k < 9; ++k) red[k] += __shfl_xor(red[k], off, 64);
        }

        // ---- softmax over 4 logits (bounded, no max-shift needed) ----
        float e0 = __expf(red[0] + ba0), e1 = __expf(red[1] + ba1);
        float e2 = __expf(red[2] + ba2), e3 = __expf(red[3] + ba3);
        float inv = 4.0f / (e0 + e1 + e2 + e3);     // fold *G
        float aw0 = e0 * inv, aw1 = e1 * inv, aw2 = e2 * inv, aw3 = e3 * inv;

        float total = red[4] * aw0 + red[5] * aw1 + red[6] * aw2 + red[7] * aw3
                    + red[8] + bh;

        st = st * (1.0f - AX_) + total * AX_;
        float no = fast_tanh_pos(fmaxf(st, 0.0f));

        // ---- publish: plain hs store (off critical path) + ONE tagged
        //      agent store (value IS the signal), fire-and-forget ----
        u64* vrow = vals + ((size_t)(t & 1) * B_N + b) * H_N;
        if (lane == 0) {
            hs[((size_t)t * B_N + b) * H_N + h] = no;   // plain, cached
            if (t + 1 < T_N)
                st64_agent(vrow + h,
                           ((u64)(u32)(t + 1) << 32) | (u64)__float_as_uint(no));
        }

        if (t + 1 == T_N) break;   // last step: epilogue kernel handles os

        // ---- next-step input prefetch + plasticity (store in flight) ----
        const float* xr = x + ((size_t)(t + 1) * B_N + b) * I_N;
        float xvn[4];
#pragma unroll
        for (int c = 0; c < 4; ++c) xvn[c] = xr[lane + 64 * c];
        float Rn = Rs[(t + 1) * B_N + b];

        float xin[4] = { xv[0] * aw0, xv[1] * aw1, xv[2] * aw2, xv[3] * aw3 };
        float dr = DT_ * Rcur;
        float k1n = k1 * no, k2n = k2 * no, k4n = k4 * no, k5n = k5 * no;
#pragma unroll
        for (int c = 0; c < 4; ++c) {
            float hx = fmaf(k2n, xin[c], fmaf(k0, xin[c], k1n));
            ex[c] = fmaxf(fmaf(ex[c], OMAW, fmaf(dr, hx, bwx[c])), 0.0f);
        }
#pragma unroll
        for (int c = 0; c < 8; ++c) {
            float hh = fmaf(k5n, outp[c], fmaf(k3, outp[c], k4n));
            float a = se[c] * OMAW, p = fmaf(dr, hh, bwh[c]);
            float r;
            if (c <= 5)      r = fmaxf(a + p, 0.0f);
            else if (c == 7) r = fminf(a - p, 0.0f);
            else             r = (lane <= 24) ? fmaxf(a + p, 0.0f)
                                              : fminf(a - p, 0.0f);
            if (c == c_d && lane == dl) r = 0.0f;   // keep diagonal at 0
            se[c] = r;
        }

        // ---- wave 0: poll line `lane` (8 contiguous tagged u64) ----
        if (wid == 0) {
            const u64* pline = vrow + (lane << 3);
            const u32 want = (u32)(t + 1);
            float v[8];
            u32 done = 0;
            while (true) {
#pragma unroll
                for (int c = 0; c < 8; ++c) {
                    if (!((done >> c) & 1u)) {
                        u64 pk = ld64_agent(pline + c);
                        if ((u32)(pk >> 32) == want) {
                            v[c] = __uint_as_float((u32)pk);
                            done |= (1u << c);
                        }
                    }
                }
                if (__all(done == 0xFFu)) break;
                __builtin_amdgcn_s_sleep(1);   // backoff: let stores land
            }
            float* sb = s_out[t & 1];
#pragma unroll
            for (int c = 0; c < 8; ++c) sb[(lane << 3) + c] = v[c];
        }
        __syncthreads();   // single barrier/step (double-buffered s_out)

        const float* sb = s_out[t & 1];
#pragma unroll
        for (int c = 0; c < 8; ++c) outp[c] = sb[lane + 64 * c];
#pragma unroll
        for (int c = 0; c < 4; ++c) xv[c] = fmaxf(xvn[c], 0.0f);
        Rcur = Rn;
    }
}

// os[t,b,o] = sum_h hs[t,b,h] * relu(W_h2o[o,h]) * exist[h]
// Separate launch: kernel boundary (release at rnn_scan end, acquire at
// os_proj start) makes the plain hs stores visible to plain loads.
__global__ __launch_bounds__(512) void os_proj(
    const float* __restrict__ hs, const float* __restrict__ W_h2o,
    float* __restrict__ os)
{
    const int blk  = blockIdx.x;        // 0..511
    const int t    = blk >> 3;
    const int b    = blk & 7;
    const int o    = threadIdx.x >> 6;  // 0..7
    const int lane = threadIdx.x & 63;
    const float* hrow = hs + ((size_t)t * B_N + b) * H_N;
    float acc = 0.0f;
#pragma unroll
    for (int c = 0; c < 7; ++c) {       // c==7 has no exist
        int j = lane + 64 * c;
        float w = fmaxf(W_h2o[o * H_N + j], 0.0f);
        if (j >= 410) w = 0.0f;
        acc = fmaf(hrow[j], w, acc);
    }
#pragma unroll
    for (int off = 32; off >= 1; off >>= 1) acc += __shfl_xor(acc, off, 64);
    if (lane == 0) os[t * (B_N * O_N) + b * O_N + o] = acc;
}

extern "C" void kernel_launch(void* const* d_in, const int* in_sizes, int n_in,
                              void* d_out, int out_size, void* d_ws, size_t ws_size,
                              hipStream_t stream) {
    (void)in_sizes; (void)n_in; (void)out_size; (void)ws_size;
    const float* x      = (const float*)d_in[0];
    const float* Rs     = (const float*)d_in[1];
    const float* W_x2h  = (const float*)d_in[2];
    const float* W_h2h  = (const float*)d_in[3];
    const float* b_h2h  = (const float*)d_in[4];
    const float* W_h2o  = (const float*)d_in[5];
    const float* W_attn = (const float*)d_in[6];
    const float* b_attn = (const float*)d_in[7];
    const float* kappa  = (const float*)d_in[8];
    float* os = (float*)d_out;                       // [T][B][O]
    float* hs = (float*)d_out + T_N * B_N * O_N;     // [T][B][H]
    u64* vals = (u64*)d_ws;                          // [2][8][512] u64 = 64 KB

    // zero the tagged comm words every call (tag 0 != any wanted tag)
    hipMemsetAsync(d_ws, 0, 2 * B_N * H_N * sizeof(u64), stream);
    rnn_scan<<<dim3(256), dim3(1024), 0, stream>>>(
        x, Rs, W_x2h, W_h2h, b_h2h, W_attn, b_attn, kappa, hs, vals);
    os_proj<<<dim3(512), dim3(512), 0, stream>>>(hs, W_h2o, os);
}